// Round 14
// baseline (62.069 us; speedup 1.0000x reference)
//
#include <hip/hip_runtime.h>
#include <hip/hip_bf16.h>

#define H 768
#define LDX 1536          // Xcat/K of g2 (width term folded into table)
#define SEQLEN 512
#define NSPAN 128

typedef __attribute__((ext_vector_type(8))) short s16x8;
typedef __attribute__((ext_vector_type(4))) float f32x4;

#define MFMA_BF16 __builtin_amdgcn_mfma_f32_16x16x32_bf16

__device__ __forceinline__ short f2bf(float f) {
    __hip_bfloat16 h = __float2bfloat16(f);
    return *reinterpret_cast<short*>(&h);
}
__device__ __forceinline__ float bf2f(short s) {
    unsigned int u = ((unsigned int)(unsigned short)s) << 16;
    return __builtin_bit_cast(float, u);
}

// ---------------------------------------------------------------------------
// 32x32 MFMA step (r9-proven). buf: A rows at [0,4096), B rows at [4096,8192);
// row = 128B; XOR swizzle (slot ^ row&7) -> conflict-free ds_read_b128.
// ---------------------------------------------------------------------------
__device__ __forceinline__ void mstep32(const char* buf, int w, int r, int hi,
                                        f32x4& a0, f32x4& a1)
{
    #pragma unroll
    for (int kc = 0; kc < 2; ++kc) {
        const int ko = kc*64 + hi*16;
        const int ra0 = r, ra1 = 16 + r, rb = w*16 + r;
        s16x8 av0 = *(const s16x8*)(buf + ra0*128 + (ko ^ ((ra0 & 7) << 4)));
        s16x8 av1 = *(const s16x8*)(buf + ra1*128 + (ko ^ ((ra1 & 7) << 4)));
        s16x8 bv  = *(const s16x8*)(buf + 4096 + rb*128 + (ko ^ ((rb & 7) << 4)));
        a0 = MFMA_BF16(av0, bv, a0, 0, 0, 0);
        a1 = MFMA_BF16(av1, bv, a1, 0, 0, 0);
    }
}

#define SLOAD(P, K0)                                                           \
    P##0 = *(const s16x8*)(gA0 + (K0));                                        \
    P##1 = *(const s16x8*)(gA1 + (K0));                                        \
    P##2 = *(const s16x8*)(gB0 + (K0));                                        \
    P##3 = *(const s16x8*)(gB1 + (K0));

#define SWRITE(P, BUF)                                                         \
    *(s16x8*)((BUF) + dA0) = P##0;                                             \
    *(s16x8*)((BUF) + dA1) = P##1;                                             \
    *(s16x8*)((BUF) + dB0) = P##2;                                             \
    *(s16x8*)((BUF) + dB1) = P##3;

// ---------------------------------------------------------------------------
// 32x32 GEMM tile, 128 threads (2 waves; wave w owns cols w*16..+15), BK=64.
// r9's exact race-free reg-staged double-buffer pipeline: only __syncthreads
// + compiler-tracked data deps (no manual vmcnt).
// ---------------------------------------------------------------------------
__device__ __forceinline__ void gemm3232(
    short* ldsb,                       // 2 x 8192 bytes
    const short* __restrict__ A, int ldA, int am0,
    const short* __restrict__ Wt, int ldW, int n0,
    int nsteps, int tid,
    f32x4& a0, f32x4& a1)
{
    const int w = tid >> 6, l = tid & 63;
    const int r = l & 15, hi = l >> 4;

    const int rr = tid >> 3, sl = tid & 7;
    const short* gA0 = A + (size_t)(am0 + rr) * ldA + ((sl ^ (rr & 7)) << 3);
    const short* gA1 = A + (size_t)(am0 + rr + 16) * ldA + ((sl ^ (rr & 7)) << 3);
    const short* gB0 = Wt + (size_t)(n0 + rr) * ldW + ((sl ^ (rr & 7)) << 3);
    const short* gB1 = Wt + (size_t)(n0 + rr + 16) * ldW + ((sl ^ (rr & 7)) << 3);
    const int dA0 = rr*128 + sl*16,        dA1 = (rr+16)*128 + sl*16;
    const int dB0 = 4096 + rr*128 + sl*16, dB1 = 4096 + (rr+16)*128 + sl*16;
    char* b0 = (char*)ldsb;
    char* b1 = (char*)ldsb + 8192;

    s16x8 Pa0, Pa1, Pa2, Pa3;
    s16x8 Pb0, Pb1, Pb2, Pb3;

    SLOAD(Pa, 0)
    SWRITE(Pa, b0)
    SLOAD(Pa, 64)
    __syncthreads();
    for (int s = 0; s < nsteps; s += 2) {
        if (s + 2 < nsteps) { SLOAD(Pb, 64*(s+2)) }
        mstep32(b0, w, r, hi, a0, a1);
        if (s + 1 < nsteps) { SWRITE(Pa, b1) }
        __syncthreads();
        if (s + 1 < nsteps) {
            if (s + 3 < nsteps) { SLOAD(Pa, 64*(s+3)) }
            mstep32(b1, w, r, hi, a0, a1);
            if (s + 2 < nsteps) { SWRITE(Pb, b0) }
            __syncthreads();
        }
    }
}

// ---------------------------------------------------------------------------
// P0: weight transposes -> bf16 [n][k]; gather seq -> Xg bf16; width table.
// blocks: [0,2304) Ws/We/Wa+Wc/Wb-Wc | [2304,3456) WtOut^T (rows<1536) |
//         [3456,3712) gather | [3712] width table T[11][768]
// ---------------------------------------------------------------------------
__global__ __launch_bounds__(256) void k_prep(
    const float* __restrict__ seq,
    const int* __restrict__ starts, const int* __restrict__ ends,
    const float* __restrict__ Ws, const float* __restrict__ We,
    const float* __restrict__ W1, const float* __restrict__ Wout,
    const float* __restrict__ wemb, const float* __restrict__ bout,
    short* __restrict__ WtSE, short* __restrict__ WtAB,
    short* __restrict__ WtOut, short* __restrict__ Xg,
    float* __restrict__ Tbl)
{
    const int b = blockIdx.x;
    const int tid = threadIdx.x;

    if (b < 2304) {                       // Ws/We/Wa+Wc/Wb-Wc transposes
        const int sec = b / 576;
        const int t = b % 576;
        const int kt = t / 24, nt = t % 24;
        __shared__ float tile[32][33];
        const int kk = tid >> 3;
        const int c4 = (tid & 7) << 2;
        const int srow = kt * 32 + kk, scol = nt * 32 + c4;
        float4 v;
        if (sec == 0)      v = *(const float4*)(Ws + (size_t)srow * H + scol);
        else if (sec == 1) v = *(const float4*)(We + (size_t)srow * H + scol);
        else {
            const float* base = W1 + (size_t)(sec == 2 ? 0 : H) * H;
            float4 u = *(const float4*)(base + (size_t)srow * H + scol);
            float4 c = *(const float4*)(W1 + (size_t)2*H*H + (size_t)srow * H + scol);
            const float sg = (sec == 2) ? 1.f : -1.f;
            v = make_float4(fmaf(sg,c.x,u.x), fmaf(sg,c.y,u.y),
                            fmaf(sg,c.z,u.z), fmaf(sg,c.w,u.w));
        }
        tile[kk][c4+0]=v.x; tile[kk][c4+1]=v.y; tile[kk][c4+2]=v.z; tile[kk][c4+3]=v.w;
        __syncthreads();
        short* dst = (sec < 2 ? WtSE : WtAB) + (size_t)(sec & 1) * H * H;
        const int nn = tid >> 3;
        short4 o;
        o.x = f2bf(tile[c4+0][nn]); o.y = f2bf(tile[c4+1][nn]);
        o.z = f2bf(tile[c4+2][nn]); o.w = f2bf(tile[c4+3][nn]);
        *(short4*)(dst + (size_t)(nt*32 + nn) * H + kt*32 + c4) = o;
    } else if (b < 3456) {                // Wout^T -> [768][1536] (rows < 1536)
        const int t = b - 2304;
        const int nt = t / 48, kt = t % 48;
        __shared__ float tile[32][33];
        const int kk = tid >> 3;
        const int c4 = (tid & 7) << 2;
        const int srow = kt * 32 + kk, scol = nt * 32 + c4;
        float4 v = *(const float4*)(Wout + (size_t)srow * H + scol);
        tile[kk][c4+0]=v.x; tile[kk][c4+1]=v.y; tile[kk][c4+2]=v.z; tile[kk][c4+3]=v.w;
        __syncthreads();
        const int nn = tid >> 3;
        short4 o;
        o.x = f2bf(tile[c4+0][nn]); o.y = f2bf(tile[c4+1][nn]);
        o.z = f2bf(tile[c4+2][nn]); o.w = f2bf(tile[c4+3][nn]);
        *(short4*)(WtOut + (size_t)(nt*32 + nn) * LDX + kt*32 + c4) = o;
    } else if (b < 3712) {                // gather: Xg[0:512)=starts, [512:1024)=ends
        const int gr = (b - 3456) * 4 + (tid >> 6);
        const int c = tid & 63;
        const int spanrow = gr & 511;
        const int idx = (gr < 512) ? starts[spanrow] : ends[spanrow];
        const size_t base = ((size_t)(spanrow >> 7) * SEQLEN + idx) * H;
        #pragma unroll
        for (int i = 0; i < 12; ++i) {
            const int col = c + i*64;
            Xg[(size_t)gr * H + col] = f2bf(seq[base + col]);
        }
    } else {                              // width table T[w][n] = wemb[w]@Wout_c + bout
        __shared__ float we_s[11*30];
        for (int t = tid; t < 11*30; t += 256) we_s[t] = wemb[t];
        __syncthreads();
        for (int n = tid; n < 768; n += 256) {
            float wcol[30];
            #pragma unroll
            for (int k = 0; k < 30; ++k)
                wcol[k] = Wout[(size_t)(1536 + k) * H + n];
            const float bv = bout[n];
            for (int wd = 0; wd < 11; ++wd) {
                float s = bv;
                #pragma unroll
                for (int k = 0; k < 30; ++k)
                    s = fmaf(we_s[wd*30 + k], wcol[k], s);
                Tbl[wd*768 + n] = s;
            }
        }
    }
}

// ---------------------------------------------------------------------------
// G1: Xcat[:, gc] = Xg(half) @ WtSE^T + bias   (N = 1536, 48 col-tiles of 32)
// ---------------------------------------------------------------------------
__global__ __launch_bounds__(128) void k_g1(
    const short* __restrict__ Xg, const short* __restrict__ WtSE,
    const float* __restrict__ bs, const float* __restrict__ be,
    short* __restrict__ Xcat)
{
    __shared__ __align__(16) short lds[2][4096];
    const int tid = threadIdx.x;
    const int bm = blockIdx.x, n0 = blockIdx.y * 32;
    const int am0 = (n0 >= 768 ? 512 : 0) + bm * 32;

    f32x4 a0 = {}, a1 = {};
    gemm3232(&lds[0][0], Xg, H, am0, WtSE, H, n0, 12, tid, a0, a1);

    const int w = tid >> 6, l = tid & 63;
    const int r = l & 15, hi = l >> 4;
    const int gc = n0 + w*16 + r;
    const float bv = (gc < 768) ? bs[gc] : be[gc - 768];
    const int r0 = bm*32 + hi*4, r1 = r0 + 16;
    #pragma unroll
    for (int rg = 0; rg < 4; ++rg) {
        Xcat[(size_t)(r0 + rg) * LDX + gc] = f2bf(a0[rg] + bv);
        Xcat[(size_t)(r1 + rg) * LDX + gc] = f2bf(a1[rg] + bv);
    }
}

// ---------------------------------------------------------------------------
// G2: SR = Xcat(K=1536) @ WtOut^T + T[width(row)]   (24 K-steps)
// ---------------------------------------------------------------------------
__global__ __launch_bounds__(128) void k_g2(
    const short* __restrict__ Xcat, const short* __restrict__ WtOut,
    const int* __restrict__ starts, const int* __restrict__ ends,
    const float* __restrict__ Tbl, short* __restrict__ SR)
{
    __shared__ __align__(16) short lds[2][4096];
    const int tid = threadIdx.x;
    const int bm = blockIdx.x, n0 = blockIdx.y * 32;

    f32x4 a0 = {}, a1 = {};
    gemm3232(&lds[0][0], Xcat, LDX, bm*32, WtOut, LDX, n0, 24, tid, a0, a1);

    const int w = tid >> 6, l = tid & 63;
    const int r = l & 15, hi = l >> 4;
    const int gc = n0 + w*16 + r;
    const int r0 = bm*32 + hi*4, r1 = r0 + 16;
    #pragma unroll
    for (int rg = 0; rg < 4; ++rg) {
        int wd0 = ends[r0+rg] - starts[r0+rg];
        wd0 = wd0 < 0 ? 0 : (wd0 > 10 ? 10 : wd0);
        int wd1 = ends[r1+rg] - starts[r1+rg];
        wd1 = wd1 < 0 ? 0 : (wd1 > 10 ? 10 : wd1);
        SR[(size_t)(r0 + rg) * H + gc] = f2bf(a0[rg] + Tbl[wd0*768 + gc]);
        SR[(size_t)(r1 + rg) * H + gc] = f2bf(a1[rg] + Tbl[wd1*768 + gc]);
    }
}

// ---------------------------------------------------------------------------
// G3: y<48: AB[:, gc] = SR @ WtAB^T (+b1 for cols<768)   [fp32 out]
//     y==48: mention = SR @ Wm + b_ment
// ---------------------------------------------------------------------------
__global__ __launch_bounds__(128) void k_g3(
    const short* __restrict__ SR, const short* __restrict__ WtAB,
    const float* __restrict__ b1, const float* __restrict__ Wm,
    const float* __restrict__ bment,
    float* __restrict__ AB, float* __restrict__ mention)
{
    const int tid = threadIdx.x;
    const int bm = blockIdx.x;

    if (blockIdx.y == 48) {               // mention scores, 32 rows per block
        const int w = tid >> 6, l = tid & 63;
        const int rows0 = bm*32 + w*16;
        const float bm_add = bment[0];
        for (int rr = 0; rr < 16; ++rr) {
            const int row = rows0 + rr;
            float p = 0.f;
            #pragma unroll
            for (int kk = 0; kk < 12; ++kk) {
                const int k = kk*64 + l;
                p = fmaf(bf2f(SR[(size_t)row * H + k]), Wm[k], p);
            }
            #pragma unroll
            for (int off = 32; off; off >>= 1) p += __shfl_down(p, off);
            if (l == 0) mention[row] = p + bm_add;
        }
        return;
    }

    __shared__ __align__(16) short lds[2][4096];
    const int n0 = blockIdx.y * 32;

    f32x4 a0 = {}, a1 = {};
    gemm3232(&lds[0][0], SR, H, bm*32, WtAB, H, n0, 12, tid, a0, a1);

    const int w = tid >> 6, l = tid & 63;
    const int r = l & 15, hi = l >> 4;
    const int gc = n0 + w*16 + r;
    const float bv = (gc < 768) ? b1[gc] : 0.f;
    const int r0 = bm*32 + hi*4, r1 = r0 + 16;
    #pragma unroll
    for (int rg = 0; rg < 4; ++rg) {
        AB[(size_t)(r0 + rg) * 1536 + gc] = a0[rg] + bv;
        AB[(size_t)(r1 + rg) * 1536 + gc] = a1[rg] + bv;
    }
}

// ---------------------------------------------------------------------------
// G4: pair[b,i,j] = (j<i) ? sum_h relu(AI+BJ)*W2[h] + b2 : 0  (r9-proven)
// ---------------------------------------------------------------------------
__global__ __launch_bounds__(256) void k_pair(
    const float* __restrict__ AB, const float* __restrict__ W2,
    const float* __restrict__ b2, float* __restrict__ pair)
{
    const int tid = threadIdx.x;
    const int bx = blockIdx.x & 7, by = blockIdx.x >> 3;
    const int bz = blockIdx.y;

    const int tx = tid & 15, ty = tid >> 4;
    const int i = by * 16 + ty, j = bx * 16 + tx;
    float* outp = pair + ((size_t)bz * NSPAN + i) * NSPAN + j;

    if (bx > by) { *outp = 0.f; return; }

    __shared__ __align__(16) float Ais[16][68];
    __shared__ __align__(16) float Bjs[16][68];
    __shared__ __align__(16) float w2s[768];
    for (int q = tid; q < 768; q += 256) w2s[q] = W2[q];

    const int sr = tid >> 4, sc = (tid & 15) << 2;
    const float* aSrc = AB + ((size_t)bz*NSPAN + by*16 + sr)*1536 + sc;
    const float* bSrc = AB + ((size_t)bz*NSPAN + bx*16 + sr)*1536 + 768 + sc;
    float acc = 0.f;

    float4 ra = *(const float4*)(aSrc);
    float4 rb = *(const float4*)(bSrc);

    for (int ch = 0; ch < 12; ++ch) {
        __syncthreads();
        *(float4*)&Ais[sr][sc] = ra;
        *(float4*)&Bjs[sr][sc] = rb;
        __syncthreads();
        if (ch < 11) {
            ra = *(const float4*)(aSrc + (ch+1)*64);
            rb = *(const float4*)(bSrc + (ch+1)*64);
        }
        #pragma unroll
        for (int hq = 0; hq < 16; ++hq) {
            float4 a = *(const float4*)&Ais[ty][hq << 2];
            float4 b = *(const float4*)&Bjs[tx][hq << 2];
            float4 wv = *(const float4*)&w2s[ch*64 + (hq << 2)];
            acc = fmaf(fmaxf(a.x + b.x, 0.f), wv.x, acc);
            acc = fmaf(fmaxf(a.y + b.y, 0.f), wv.y, acc);
            acc = fmaf(fmaxf(a.z + b.z, 0.f), wv.z, acc);
            acc = fmaf(fmaxf(a.w + b.w, 0.f), wv.w, acc);
        }
    }
    *outp = (j < i) ? (acc + b2[0]) : 0.f;
}

// ---------------------------------------------------------------------------
extern "C" void kernel_launch(void* const* d_in, const int* in_sizes, int n_in,
                              void* d_out, int out_size, void* d_ws, size_t ws_size,
                              hipStream_t stream)
{
    const float* seq    = (const float*)d_in[0];
    const int*   starts = (const int*)  d_in[1];
    const int*   ends   = (const int*)  d_in[2];
    const float* Ws     = (const float*)d_in[3];
    const float* bs     = (const float*)d_in[4];
    const float* We     = (const float*)d_in[5];
    const float* be     = (const float*)d_in[6];
    const float* wemb   = (const float*)d_in[7];
    const float* Wout   = (const float*)d_in[8];
    const float* bout   = (const float*)d_in[9];
    const float* Wm     = (const float*)d_in[10];
    const float* bment  = (const float*)d_in[11];
    const float* W1     = (const float*)d_in[12];
    const float* b1     = (const float*)d_in[13];
    const float* W2     = (const float*)d_in[14];
    const float* b2     = (const float*)d_in[15];

    float* ws = (float*)d_ws;
    float* AB    = ws;                          // 512*1536 fp32
    short* Xg    = (short*)(ws + 786432);       // 1024*768 bf16
    short* Xcat  = Xg + 786432;                 // 512*1536 bf16
    short* SR    = Xcat + 786432;               // 512*768  bf16
    short* WtSE  = SR + 393216;                 // 1536*768 bf16
    short* WtAB  = WtSE + 1179648;              // 1536*768 bf16
    short* WtOut = WtAB + 1179648;              // 768*1536 bf16
    float* Tbl   = (float*)(WtOut + 1179648);   // 11*768 fp32

    float* out_mention = (float*)d_out;         // 512
    float* out_pair    = (float*)d_out + 512;   // 4*128*128

    hipLaunchKernelGGL(k_prep, dim3(3713), dim3(256), 0, stream,
                       seq, starts, ends, Ws, We, W1, Wout, wemb, bout,
                       WtSE, WtAB, WtOut, Xg, Tbl);
    hipLaunchKernelGGL(k_g1, dim3(16, 48), dim3(128), 0, stream,
                       Xg, WtSE, bs, be, Xcat);
    hipLaunchKernelGGL(k_g2, dim3(16, 24), dim3(128), 0, stream,
                       Xcat, WtOut, starts, ends, Tbl, SR);
    hipLaunchKernelGGL(k_g3, dim3(16, 49), dim3(128), 0, stream,
                       SR, WtAB, b1, Wm, bment, AB, out_mention);
    hipLaunchKernelGGL(k_pair, dim3(64, 4), dim3(256), 0, stream,
                       AB, W2, b2, out_pair);
}

// Round 15
// 46.864 us; speedup vs baseline: 1.3245x; 1.3245x over previous
//
#include <hip/hip_runtime.h>
#include <hip/hip_bf16.h>

#define H 768
#define K2P 1600          // 768 + 768 + 64 (width 30 padded to 64)
#define SEQLEN 512
#define NSPAN 128

typedef __attribute__((ext_vector_type(8))) short s16x8;
typedef __attribute__((ext_vector_type(4))) float f32x4;

#define MFMA_BF16 __builtin_amdgcn_mfma_f32_16x16x32_bf16

__device__ __forceinline__ short f2bf(float f) {
    __hip_bfloat16 h = __float2bfloat16(f);
    return *reinterpret_cast<short*>(&h);
}
__device__ __forceinline__ float bf2f(short s) {
    unsigned int u = ((unsigned int)(unsigned short)s) << 16;
    return __builtin_bit_cast(float, u);
}

// ---------------------------------------------------------------------------
// 32x32 GEMM tile, 128 threads (2 waves; wave w owns cols w*16..+15), BK=64.
// r9-proven race-free reg-staged double-buffer pipeline: only __syncthreads +
// compiler-tracked data deps (no manual vmcnt). LDS (16 KB = 2 x 8 KB):
// A rows at [0,4096), B rows at [4096,8192); row = 128B; XOR swizzle
// (slot ^ row&7) keeps ds_read_b128 conflict-free.
// ---------------------------------------------------------------------------
__device__ __forceinline__ void mstep32(const char* buf, int w, int r, int hi,
                                        f32x4& a0, f32x4& a1)
{
    #pragma unroll
    for (int kc = 0; kc < 2; ++kc) {
        const int ko = kc*64 + hi*16;
        const int ra0 = r, ra1 = 16 + r, rb = w*16 + r;
        s16x8 av0 = *(const s16x8*)(buf + ra0*128 + (ko ^ ((ra0 & 7) << 4)));
        s16x8 av1 = *(const s16x8*)(buf + ra1*128 + (ko ^ ((ra1 & 7) << 4)));
        s16x8 bv  = *(const s16x8*)(buf + 4096 + rb*128 + (ko ^ ((rb & 7) << 4)));
        a0 = MFMA_BF16(av0, bv, a0, 0, 0, 0);
        a1 = MFMA_BF16(av1, bv, a1, 0, 0, 0);
    }
}

#define SLOAD(P, K0)                                                           \
    P##0 = *(const s16x8*)(gA0 + (K0));                                        \
    P##1 = *(const s16x8*)(gA1 + (K0));                                        \
    P##2 = *(const s16x8*)(gB0 + (K0));                                        \
    P##3 = *(const s16x8*)(gB1 + (K0));

#define SWRITE(P, BUF)                                                         \
    *(s16x8*)((BUF) + dA0) = P##0;                                             \
    *(s16x8*)((BUF) + dA1) = P##1;                                             \
    *(s16x8*)((BUF) + dB0) = P##2;                                             \
    *(s16x8*)((BUF) + dB1) = P##3;

__device__ __forceinline__ void gemm3232(
    short* ldsb,                       // 2 x 8192 bytes
    const short* __restrict__ A, int ldA, int am0,
    const short* __restrict__ Wt, int ldW, int n0,
    int nsteps, int tid,
    f32x4& a0, f32x4& a1)
{
    const int w = tid >> 6, l = tid & 63;
    const int r = l & 15, hi = l >> 4;

    const int rr = tid >> 3, sl = tid & 7;   // rr 0..15, 16B slot sl
    const short* gA0 = A + (size_t)(am0 + rr) * ldA + ((sl ^ (rr & 7)) << 3);
    const short* gA1 = A + (size_t)(am0 + rr + 16) * ldA + ((sl ^ (rr & 7)) << 3);
    const short* gB0 = Wt + (size_t)(n0 + rr) * ldW + ((sl ^ (rr & 7)) << 3);
    const short* gB1 = Wt + (size_t)(n0 + rr + 16) * ldW + ((sl ^ (rr & 7)) << 3);
    const int dA0 = rr*128 + sl*16,        dA1 = (rr+16)*128 + sl*16;
    const int dB0 = 4096 + rr*128 + sl*16, dB1 = 4096 + (rr+16)*128 + sl*16;
    char* b0 = (char*)ldsb;
    char* b1 = (char*)ldsb + 8192;

    s16x8 Pa0, Pa1, Pa2, Pa3;
    s16x8 Pb0, Pb1, Pb2, Pb3;

    SLOAD(Pa, 0)
    SWRITE(Pa, b0)
    SLOAD(Pa, 64)
    __syncthreads();
    for (int s = 0; s < nsteps; s += 2) {
        if (s + 2 < nsteps) { SLOAD(Pb, 64*(s+2)) }
        mstep32(b0, w, r, hi, a0, a1);
        if (s + 1 < nsteps) { SWRITE(Pa, b1) }
        __syncthreads();
        if (s + 1 < nsteps) {
            if (s + 3 < nsteps) { SLOAD(Pa, 64*(s+3)) }
            mstep32(b1, w, r, hi, a0, a1);
            if (s + 2 < nsteps) { SWRITE(Pb, b0) }
            __syncthreads();
        }
    }
}

// ---------------------------------------------------------------------------
// P0: weight transposes -> bf16 [n][k]; gather seq -> Xg bf16; width cols.
// ---------------------------------------------------------------------------
__global__ __launch_bounds__(256) void k_prep(
    const float* __restrict__ seq,
    const int* __restrict__ starts, const int* __restrict__ ends,
    const float* __restrict__ Ws, const float* __restrict__ We,
    const float* __restrict__ W1, const float* __restrict__ Wout,
    const float* __restrict__ wemb,
    short* __restrict__ WtSE, short* __restrict__ WtAB,
    short* __restrict__ WtOut, short* __restrict__ Xg, short* __restrict__ Xcat)
{
    const int b = blockIdx.x;
    const int tid = threadIdx.x;

    if (b < 2304) {                       // Ws/We/Wa+Wc/Wb-Wc transposes
        const int sec = b / 576;
        const int t = b % 576;
        const int kt = t / 24, nt = t % 24;
        __shared__ float tile[32][33];
        const int kk = tid >> 3;
        const int c4 = (tid & 7) << 2;
        const int srow = kt * 32 + kk, scol = nt * 32 + c4;
        float4 v;
        if (sec == 0)      v = *(const float4*)(Ws + (size_t)srow * H + scol);
        else if (sec == 1) v = *(const float4*)(We + (size_t)srow * H + scol);
        else {
            const float* base = W1 + (size_t)(sec == 2 ? 0 : H) * H;
            float4 u = *(const float4*)(base + (size_t)srow * H + scol);
            float4 c = *(const float4*)(W1 + (size_t)2*H*H + (size_t)srow * H + scol);
            const float sg = (sec == 2) ? 1.f : -1.f;
            v = make_float4(fmaf(sg,c.x,u.x), fmaf(sg,c.y,u.y),
                            fmaf(sg,c.z,u.z), fmaf(sg,c.w,u.w));
        }
        tile[kk][c4+0]=v.x; tile[kk][c4+1]=v.y; tile[kk][c4+2]=v.z; tile[kk][c4+3]=v.w;
        __syncthreads();
        short* dst = (sec < 2 ? WtSE : WtAB) + (size_t)(sec & 1) * H * H;
        const int nn = tid >> 3;
        short4 o;
        o.x = f2bf(tile[c4+0][nn]); o.y = f2bf(tile[c4+1][nn]);
        o.z = f2bf(tile[c4+2][nn]); o.w = f2bf(tile[c4+3][nn]);
        *(short4*)(dst + (size_t)(nt*32 + nn) * H + kt*32 + c4) = o;
    } else if (b < 3504) {                // Wout^T -> [768][1600], zero-padded
        const int t = b - 2304;
        const int nt = t / 50, kt = t % 50;
        __shared__ float tile[32][33];
        const int kk = tid >> 3;
        const int c4 = (tid & 7) << 2;
        const int srow = kt * 32 + kk, scol = nt * 32 + c4;
        float4 v = make_float4(0.f, 0.f, 0.f, 0.f);
        if (srow < 1566) v = *(const float4*)(Wout + (size_t)srow * H + scol);
        tile[kk][c4+0]=v.x; tile[kk][c4+1]=v.y; tile[kk][c4+2]=v.z; tile[kk][c4+3]=v.w;
        __syncthreads();
        const int nn = tid >> 3;
        short4 o;
        o.x = f2bf(tile[c4+0][nn]); o.y = f2bf(tile[c4+1][nn]);
        o.z = f2bf(tile[c4+2][nn]); o.w = f2bf(tile[c4+3][nn]);
        *(short4*)(WtOut + (size_t)(nt*32 + nn) * K2P + kt*32 + c4) = o;
    } else if (b < 3760) {                // gather: Xg[0:512)=starts, [512:1024)=ends
        const int gr = (b - 3504) * 4 + (tid >> 6);
        const int c = tid & 63;
        const int spanrow = gr & 511;
        const int idx = (gr < 512) ? starts[spanrow] : ends[spanrow];
        const size_t base = ((size_t)(spanrow >> 7) * SEQLEN + idx) * H;
        #pragma unroll
        for (int i = 0; i < 12; ++i) {
            const int col = c + i*64;
            Xg[(size_t)gr * H + col] = f2bf(seq[base + col]);
        }
    } else {                              // Xcat width-emb cols 1536..1599
        const int t = (b - 3760) * 256 + tid;
        const int row = t >> 6, c = t & 63;
        int wd = ends[row] - starts[row];
        wd = wd < 0 ? 0 : (wd > 10 ? 10 : wd);
        Xcat[(size_t)row * K2P + 1536 + c] = (c < 30) ? f2bf(wemb[wd*30 + c]) : (short)0;
    }
}

// ---------------------------------------------------------------------------
// G1: Xcat[:, gc] = Xg(half) @ WtSE^T + bias   (N = 1536, 48 col-tiles of 32)
// ---------------------------------------------------------------------------
__global__ __launch_bounds__(128) void k_g1(
    const short* __restrict__ Xg, const short* __restrict__ WtSE,
    const float* __restrict__ bs, const float* __restrict__ be,
    short* __restrict__ Xcat)
{
    __shared__ __align__(16) short lds[2][4096];
    const int tid = threadIdx.x;
    const int bm = blockIdx.x, n0 = blockIdx.y * 32;
    const int am0 = (n0 >= 768 ? 512 : 0) + bm * 32;

    f32x4 a0 = {}, a1 = {};
    gemm3232(&lds[0][0], Xg, H, am0, WtSE, H, n0, 12, tid, a0, a1);

    const int w = tid >> 6, l = tid & 63;
    const int r = l & 15, hi = l >> 4;
    const int gc = n0 + w*16 + r;
    const float bv = (gc < 768) ? bs[gc] : be[gc - 768];
    const int r0 = bm*32 + hi*4, r1 = r0 + 16;
    #pragma unroll
    for (int rg = 0; rg < 4; ++rg) {
        Xcat[(size_t)(r0 + rg) * K2P + gc] = f2bf(a0[rg] + bv);
        Xcat[(size_t)(r1 + rg) * K2P + gc] = f2bf(a1[rg] + bv);
    }
}

// ---------------------------------------------------------------------------
// G2: SR = Xcat(K=1600) @ WtOut^T + b_out   (24 col-tiles of 32)
// ---------------------------------------------------------------------------
__global__ __launch_bounds__(128) void k_g2(
    const short* __restrict__ Xcat, const short* __restrict__ WtOut,
    const float* __restrict__ bout, short* __restrict__ SR)
{
    __shared__ __align__(16) short lds[2][4096];
    const int tid = threadIdx.x;
    const int bm = blockIdx.x, n0 = blockIdx.y * 32;

    f32x4 a0 = {}, a1 = {};
    gemm3232(&lds[0][0], Xcat, K2P, bm*32, WtOut, K2P, n0, 25, tid, a0, a1);

    const int w = tid >> 6, l = tid & 63;
    const int r = l & 15, hi = l >> 4;
    const int gc = n0 + w*16 + r;
    const float bv = bout[gc];
    const int r0 = bm*32 + hi*4, r1 = r0 + 16;
    #pragma unroll
    for (int rg = 0; rg < 4; ++rg) {
        SR[(size_t)(r0 + rg) * H + gc] = f2bf(a0[rg] + bv);
        SR[(size_t)(r1 + rg) * H + gc] = f2bf(a1[rg] + bv);
    }
}

// ---------------------------------------------------------------------------
// G3: y<48: AB[:, gc] = SR @ WtAB^T (+b1 for cols<768)   [fp32 out]
//     y==48: mention = SR @ Wm + b_ment
// ---------------------------------------------------------------------------
__global__ __launch_bounds__(128) void k_g3(
    const short* __restrict__ SR, const short* __restrict__ WtAB,
    const float* __restrict__ b1, const float* __restrict__ Wm,
    const float* __restrict__ bment,
    float* __restrict__ AB, float* __restrict__ mention)
{
    const int tid = threadIdx.x;
    const int bm = blockIdx.x;

    if (blockIdx.y == 48) {               // mention scores, 32 rows per block
        const int w = tid >> 6, l = tid & 63;
        const int rows0 = bm*32 + w*16;
        const float bm_add = bment[0];
        for (int rr = 0; rr < 16; ++rr) {
            const int row = rows0 + rr;
            float p = 0.f;
            #pragma unroll
            for (int kk = 0; kk < 12; ++kk) {
                const int k = kk*64 + l;
                p = fmaf(bf2f(SR[(size_t)row * H + k]), Wm[k], p);
            }
            #pragma unroll
            for (int off = 32; off; off >>= 1) p += __shfl_down(p, off);
            if (l == 0) mention[row] = p + bm_add;
        }
        return;
    }

    __shared__ __align__(16) short lds[2][4096];
    const int n0 = blockIdx.y * 32;

    f32x4 a0 = {}, a1 = {};
    gemm3232(&lds[0][0], SR, H, bm*32, WtAB, H, n0, 12, tid, a0, a1);

    const int w = tid >> 6, l = tid & 63;
    const int r = l & 15, hi = l >> 4;
    const int gc = n0 + w*16 + r;
    const float bv = (gc < 768) ? b1[gc] : 0.f;
    const int r0 = bm*32 + hi*4, r1 = r0 + 16;
    #pragma unroll
    for (int rg = 0; rg < 4; ++rg) {
        AB[(size_t)(r0 + rg) * 1536 + gc] = a0[rg] + bv;
        AB[(size_t)(r1 + rg) * 1536 + gc] = a1[rg] + bv;
    }
}

// ---------------------------------------------------------------------------
// G4: pair[b,i,j] = (j<i) ? sum_h relu(AI+BJ)*W2[h] + b2 : 0
// Full 8x8 tile grid; upper tiles write zeros (no memset needed).
// Register-prefetch of next chunk overlaps global latency with compute.
// AB = [512][1536] fp32, AI at +0 (b1 folded), BJ at +768.
// ---------------------------------------------------------------------------
__global__ __launch_bounds__(256) void k_pair(
    const float* __restrict__ AB, const float* __restrict__ W2,
    const float* __restrict__ b2, float* __restrict__ pair)
{
    const int tid = threadIdx.x;
    const int bx = blockIdx.x & 7, by = blockIdx.x >> 3;
    const int bz = blockIdx.y;

    const int tx = tid & 15, ty = tid >> 4;
    const int i = by * 16 + ty, j = bx * 16 + tx;
    float* outp = pair + ((size_t)bz * NSPAN + i) * NSPAN + j;

    if (bx > by) { *outp = 0.f; return; }

    __shared__ __align__(16) float Ais[16][68];
    __shared__ __align__(16) float Bjs[16][68];
    __shared__ __align__(16) float w2s[768];
    for (int q = tid; q < 768; q += 256) w2s[q] = W2[q];

    const int sr = tid >> 4, sc = (tid & 15) << 2;
    const float* aSrc = AB + ((size_t)bz*NSPAN + by*16 + sr)*1536 + sc;
    const float* bSrc = AB + ((size_t)bz*NSPAN + bx*16 + sr)*1536 + 768 + sc;
    float acc = 0.f;

    float4 ra = *(const float4*)(aSrc);
    float4 rb = *(const float4*)(bSrc);

    for (int ch = 0; ch < 12; ++ch) {
        __syncthreads();
        *(float4*)&Ais[sr][sc] = ra;
        *(float4*)&Bjs[sr][sc] = rb;
        __syncthreads();
        if (ch < 11) {
            ra = *(const float4*)(aSrc + (ch+1)*64);
            rb = *(const float4*)(bSrc + (ch+1)*64);
        }
        #pragma unroll
        for (int hq = 0; hq < 16; ++hq) {
            float4 a = *(const float4*)&Ais[ty][hq << 2];
            float4 b = *(const float4*)&Bjs[tx][hq << 2];
            float4 wv = *(const float4*)&w2s[ch*64 + (hq << 2)];
            acc = fmaf(fmaxf(a.x + b.x, 0.f), wv.x, acc);
            acc = fmaf(fmaxf(a.y + b.y, 0.f), wv.y, acc);
            acc = fmaf(fmaxf(a.z + b.z, 0.f), wv.z, acc);
            acc = fmaf(fmaxf(a.w + b.w, 0.f), wv.w, acc);
        }
    }
    *outp = (j < i) ? (acc + b2[0]) : 0.f;
}

// ---------------------------------------------------------------------------
extern "C" void kernel_launch(void* const* d_in, const int* in_sizes, int n_in,
                              void* d_out, int out_size, void* d_ws, size_t ws_size,
                              hipStream_t stream)
{
    const float* seq    = (const float*)d_in[0];
    const int*   starts = (const int*)  d_in[1];
    const int*   ends   = (const int*)  d_in[2];
    const float* Ws     = (const float*)d_in[3];
    const float* bs     = (const float*)d_in[4];
    const float* We     = (const float*)d_in[5];
    const float* be     = (const float*)d_in[6];
    const float* wemb   = (const float*)d_in[7];
    const float* Wout   = (const float*)d_in[8];
    const float* bout   = (const float*)d_in[9];
    const float* Wm     = (const float*)d_in[10];
    const float* bment  = (const float*)d_in[11];
    const float* W1     = (const float*)d_in[12];
    const float* b1     = (const float*)d_in[13];
    const float* W2     = (const float*)d_in[14];
    const float* b2     = (const float*)d_in[15];

    float* ws = (float*)d_ws;
    float* AB    = ws;                          // 512*1536 fp32
    short* Xg    = (short*)(ws + 786432);       // 1024*768 bf16
    short* Xcat  = Xg + 786432;                 // 512*1600 bf16
    short* SR    = Xcat + 819200;               // 512*768  bf16
    short* WtSE  = SR + 393216;                 // 1536*768 bf16
    short* WtAB  = WtSE + 1179648;              // 1536*768 bf16
    short* WtOut = WtAB + 1179648;              // 768*1600 bf16

    float* out_mention = (float*)d_out;         // 512
    float* out_pair    = (float*)d_out + 512;   // 4*128*128

    hipLaunchKernelGGL(k_prep, dim3(3824), dim3(256), 0, stream,
                       seq, starts, ends, Ws, We, W1, Wout, wemb,
                       WtSE, WtAB, WtOut, Xg, Xcat);
    hipLaunchKernelGGL(k_g1, dim3(16, 48), dim3(128), 0, stream,
                       Xg, WtSE, bs, be, Xcat);
    hipLaunchKernelGGL(k_g2, dim3(16, 24), dim3(128), 0, stream,
                       Xcat, WtOut, bout, SR);
    hipLaunchKernelGGL(k_g3, dim3(16, 49), dim3(128), 0, stream,
                       SR, WtAB, b1, Wm, bment, AB, out_mention);
    hipLaunchKernelGGL(k_pair, dim3(64, 4), dim3(256), 0, stream,
                       AB, W2, b2, out_pair);
}